// Round 6
// baseline (162.248 us; speedup 1.0000x reference)
//
#include <hip/hip_runtime.h>

#define SEQ_T 2048
#define HDIM  128
#define NB    16
#define NTILES (SEQ_T / 64)          // 32 kv-tiles of 64
#define TILE_SHORTS 8192             // 16 KB per tile (64x128 bf16)
#define CHUNKS_PER_B 40              // sum over qb of ceil((2qb+2)/8)
#define SLOTS_PER_B  36              // split-chunk partial slots per batch
#define OPART_SHORTS 16384           // 128x128 bf16 per slot
#define ML_FLOATS    256             // m[128] | l[128] per slot

typedef __attribute__((ext_vector_type(8))) short short8;      // 8 bf16 (4 VGPRs)
typedef __attribute__((ext_vector_type(4))) float float4v;
typedef __attribute__((ext_vector_type(4))) unsigned int uint4v;

#define EXP2F(x) __builtin_amdgcn_exp2f(x)

__device__ __forceinline__ unsigned int bfpack2(float a, float b) {
  unsigned int ua = __builtin_bit_cast(unsigned int, a);
  unsigned int ub = __builtin_bit_cast(unsigned int, b);
  return ((ua + 0x8000u) >> 16) | ((ub + 0x8000u) & 0xFFFF0000u);
}
__device__ __forceinline__ unsigned short f2bf(float a) {
  return (unsigned short)((__builtin_bit_cast(unsigned int, a) + 0x8000u) >> 16);
}
__device__ __forceinline__ float bf2f(unsigned short h) {
  unsigned int u = ((unsigned int)h) << 16;
  return __builtin_bit_cast(float, u);
}

__device__ __forceinline__ float dpp_max16(float x) {
  int t;
  t = __builtin_amdgcn_mov_dpp(__builtin_bit_cast(int, x), 0xB1, 0xF, 0xF, true);
  x = fmaxf(x, __builtin_bit_cast(float, t));
  t = __builtin_amdgcn_mov_dpp(__builtin_bit_cast(int, x), 0x4E, 0xF, 0xF, true);
  x = fmaxf(x, __builtin_bit_cast(float, t));
  t = __builtin_amdgcn_mov_dpp(__builtin_bit_cast(int, x), 0x141, 0xF, 0xF, true);
  x = fmaxf(x, __builtin_bit_cast(float, t));
  t = __builtin_amdgcn_mov_dpp(__builtin_bit_cast(int, x), 0x140, 0xF, 0xF, true);
  x = fmaxf(x, __builtin_bit_cast(float, t));
  return x;
}
__device__ __forceinline__ float dpp_sum16(float x) {
  int t;
  t = __builtin_amdgcn_mov_dpp(__builtin_bit_cast(int, x), 0xB1, 0xF, 0xF, true);
  x += __builtin_bit_cast(float, t);
  t = __builtin_amdgcn_mov_dpp(__builtin_bit_cast(int, x), 0x4E, 0xF, 0xF, true);
  x += __builtin_bit_cast(float, t);
  t = __builtin_amdgcn_mov_dpp(__builtin_bit_cast(int, x), 0x141, 0xF, 0xF, true);
  x += __builtin_bit_cast(float, t);
  t = __builtin_amdgcn_mov_dpp(__builtin_bit_cast(int, x), 0x140, 0xF, 0xF, true);
  x += __builtin_bit_cast(float, t);
  return x;
}

// async 16B/lane global->LDS DMA; LDS image = wave-uniform base + lane*16
__device__ __forceinline__ void stage16(const unsigned short* g, unsigned short* l) {
  __builtin_amdgcn_global_load_lds(
      (const __attribute__((address_space(1))) unsigned int*)g,
      (__attribute__((address_space(3))) unsigned int*)l, 16, 0, 0);
}

// partial-slot base within a batch for split q-block qb (4..15)
__device__ __forceinline__ int slot_base(int qb) {
  return (qb < 8) ? (qb - 4) * 2 : (qb < 12) ? 8 + (qb - 8) * 3 : 20 + (qb - 12) * 4;
}

// ============================ prepass ============================
// x [B,T,384] fp32 -> kbuf/vbuf bf16 in LDS-image (swizzled) tile layouts.
__global__ __launch_bounds__(256) void prepass_kernel(const float* __restrict__ x,
                                                      unsigned short* __restrict__ kbuf,
                                                      unsigned short* __restrict__ vbuf) {
  const int n = blockIdx.x * 256 + threadIdx.x;
  const int b = n >> 15;
  const int t = (n >> 10) & 31;
  const int g = n & 1023;
  const float* xb = x + (size_t)b * (SEQ_T * 384);
  {   // K unit: r = g>>4, u = g&15
    int r = g >> 4, u = g & 15;
    const float* src = xb + (size_t)(t * 64 + r) * 384 + u * 8;
    float4v a = *(const float4v*)src;
    float4v c = *(const float4v*)(src + 4);
    uint4v pk = { bfpack2(a[0], a[1]), bfpack2(a[2], a[3]),
                  bfpack2(c[0], c[1]), bfpack2(c[2], c[3]) };
    int dst = (n & ~1023) | (r * 16 + ((u + r) & 15));
    *(uint4v*)(kbuf + (size_t)dst * 8) = pk;
  }
  {   // V unit (transposed): u = g>>7, d = g&127
    int u = g >> 7, d = g & 127;
    const float* src = xb + (size_t)(t * 64 + u * 8) * 384 + 256 + d;
    uint4v pv = { bfpack2(src[0],    src[384]),
                  bfpack2(src[768],  src[1152]),
                  bfpack2(src[1536], src[1920]),
                  bfpack2(src[2304], src[2688]) };
    int dst = (n & ~1023) | (d * 8 + ((u + d) & 7));
    *(uint4v*)(vbuf + (size_t)dst * 8) = pv;
  }
}

// ============================ chunked main kernel ============================
// 640 blocks x 512 thr. Block = (b, chunk c): 8 q-tiles (128 q-rows of q-block qb),
// kv super-iters [8k, min(8k+8, 2qb+2)). g==1 -> direct out; else bf16 partials.
__global__ __launch_bounds__(512, 4) void attn_chunk(const float* __restrict__ x,
                                                     const unsigned short* __restrict__ kbuf,
                                                     const unsigned short* __restrict__ vbuf,
                                                     unsigned short* __restrict__ Opart,
                                                     float* __restrict__ mlpart,
                                                     float* __restrict__ out) {
  const int f = blockIdx.x;
  const int b = f / CHUNKS_PER_B;
  const int c = f - b * CHUNKS_PER_B;
  int qb, k, g;
  if (c < 4)       { qb = c;                k = 0;           g = 1; }
  else if (c < 12) { int t = c - 4;  qb = 4  + (t >> 1); k = t & 1;  g = 2; }
  else if (c < 24) { int t = c - 12; qb = 8  + t / 3;    k = t % 3;  g = 3; }
  else             { int t = c - 24; qb = 12 + (t >> 2); k = t & 3;  g = 4; }
  const int sBeg = k * 8;
  const int sEnd = min(sBeg + 8, 2 * qb + 2);

  const int tid  = threadIdx.x;
  const int qt   = tid >> 6;              // wave = q-tile 0..7
  const int lane = tid & 63;
  const int low  = lane & 15;
  const int quad = lane >> 4;
  const int q0   = qb * 128 + qt * 16;    // absolute q row base of this wave

  __shared__ __align__(16) unsigned char smem[43008];
  unsigned short* Ks = (unsigned short*)smem;            // 16 KB, swizzled K tile
  unsigned short* Vt = (unsigned short*)(smem + 16384);  // 16 KB, swizzled V^T tile
  unsigned short* Ps = (unsigned short*)(smem + 32768);  // [8][16*40]

  const float* xb = x + (size_t)b * (SEQ_T * 3 * HDIM);
  const unsigned short* kt = kbuf + (size_t)b * NTILES * TILE_SHORTS;
  const unsigned short* vt = vbuf + (size_t)b * NTILES * TILE_SHORTS;

  // Q fragments, pre-scaled by 128^-0.5 * log2(e)
  const float qs = 0.08838834764831845f * 1.4426950408889634f;
  short8 qa[4];
  {
    const float* qrow = xb + (size_t)(q0 + low) * 384 + 128;
    for (int kc = 0; kc < 4; ++kc) {
      float4v f0 = *(const float4v*)(qrow + kc * 32 + quad * 8);
      float4v f1 = *(const float4v*)(qrow + kc * 32 + quad * 8 + 4);
      uint4v u = { bfpack2(f0[0] * qs, f0[1] * qs), bfpack2(f0[2] * qs, f0[3] * qs),
                   bfpack2(f1[0] * qs, f1[1] * qs), bfpack2(f1[2] * qs, f1[3] * qs) };
      qa[kc] = __builtin_bit_cast(short8, u);
    }
  }

  float4v accv[8];
  for (int i = 0; i < 8; ++i) accv[i] = (float4v){0.f, 0.f, 0.f, 0.f};
  float m_i[4] = {-1e30f, -1e30f, -1e30f, -1e30f};
  float l_i[4] = {0.f, 0.f, 0.f, 0.f};

  for (int s = sBeg; s < sEnd; ++s) {
    __syncthreads();
    {  // stage 16KB K + 16KB V for kv tile s (4 DMA instr / wave)
      const unsigned short* ksrc = kt + (size_t)s * TILE_SHORTS;
      const unsigned short* vsrc = vt + (size_t)s * TILE_SHORTS;
      int ch = qt * 2;
      stage16(ksrc + (size_t)ch * 512 + lane * 8,       Ks + ch * 512);
      stage16(ksrc + (size_t)(ch + 1) * 512 + lane * 8, Ks + (ch + 1) * 512);
      stage16(vsrc + (size_t)ch * 512 + lane * 8,       Vt + ch * 512);
      stage16(vsrc + (size_t)(ch + 1) * 512 + lane * 8, Vt + (ch + 1) * 512);
    }
    __syncthreads();

    for (int h = 0; h < 2; ++h) {
      const int c0 = s * 64 + h * 32;
      if (c0 > q0 + 15) continue;          // wave-uniform causal skip
      const int Ra = (h << 5) + low;
      const int Rb = Ra + 16;
      float4v s0 = {0.f,0.f,0.f,0.f}, s1 = {0.f,0.f,0.f,0.f};
      for (int kc = 0; kc < 4; ++kc) {
        short8 kf0 = *(const short8*)&Ks[Ra * 128 + (((kc * 4 + quad) + Ra) & 15) * 8];
        short8 kf1 = *(const short8*)&Ks[Rb * 128 + (((kc * 4 + quad) + Rb) & 15) * 8];
        s0 = __builtin_amdgcn_mfma_f32_16x16x32_bf16(qa[kc], kf0, s0, 0, 0, 0);
        s1 = __builtin_amdgcn_mfma_f32_16x16x32_bf16(qa[kc], kf1, s1, 0, 0, 0);
      }
      if (c0 + 31 > q0) {                  // diagonal tile mask
        for (int r = 0; r < 4; ++r) {
          int qrow = q0 + quad * 4 + r;
          s0[r] = (c0 + low      <= qrow) ? s0[r] : -1e30f;
          s1[r] = (c0 + 16 + low <= qrow) ? s1[r] : -1e30f;
        }
      }
      float rmax[4], alpha[4];
      for (int r = 0; r < 4; ++r) rmax[r] = dpp_max16(fmaxf(s0[r], s1[r]));
      for (int r = 0; r < 4; ++r) {
        float mn = fmaxf(m_i[r], rmax[r]);
        alpha[r] = EXP2F(m_i[r] - mn);
        m_i[r]   = mn;
      }
      for (int r = 0; r < 4; ++r) {
        s0[r] = EXP2F(s0[r] - m_i[r]);
        s1[r] = EXP2F(s1[r] - m_i[r]);
      }
      float rs[4];
      for (int r = 0; r < 4; ++r) rs[r] = dpp_sum16(s0[r] + s1[r]);
      for (int r = 0; r < 4; ++r) l_i[r] = l_i[r] * alpha[r] + rs[r];
      for (int nt = 0; nt < 8; ++nt)
        for (int r = 0; r < 4; ++r) accv[nt][r] *= alpha[r];

      unsigned short* pw = Ps + qt * 640;
      for (int r = 0; r < 4; ++r) {
        int row = quad * 4 + r;
        pw[row * 40 + low]      = f2bf(s0[r]);
        pw[row * 40 + 16 + low] = f2bf(s1[r]);
      }
      short8 pa = *(const short8*)&pw[low * 40 + quad * 8];

      const int ub = (h << 2) + quad;
      for (int nt = 0; nt < 8; ++nt) {
        int d = nt * 16 + low;
        short8 vf = *(const short8*)&Vt[d * 64 + ((ub + d) & 7) * 8];
        accv[nt] = __builtin_amdgcn_mfma_f32_16x16x32_bf16(pa, vf, accv[nt], 0, 0, 0);
      }
    }
  }

  if (g == 1) {    // unsplit: finalize directly
    float inv[4];
    for (int r = 0; r < 4; ++r) inv[r] = 1.f / l_i[r];
    float* ob = out + ((size_t)b * SEQ_T + q0) * HDIM;
    for (int nt = 0; nt < 8; ++nt)
      for (int r = 0; r < 4; ++r)
        ob[(size_t)(quad * 4 + r) * HDIM + nt * 16 + low] = accv[nt][r] * inv[r];
  } else {         // split: write unnormalized bf16 O + fp32 m,l
    const int slot = b * SLOTS_PER_B + slot_base(qb) + k;
    unsigned short* op = Opart + (size_t)slot * OPART_SHORTS + (size_t)qt * 16 * 128;
    for (int nt = 0; nt < 8; ++nt)
      for (int r = 0; r < 4; ++r)
        op[(size_t)(quad * 4 + r) * 128 + nt * 16 + low] = f2bf(accv[nt][r]);
    if (low == 0) {
      float* ml = mlpart + (size_t)slot * ML_FLOATS;
      for (int r = 0; r < 4; ++r) {
        int row = qt * 16 + quad * 4 + r;
        ml[row]       = m_i[r];
        ml[128 + row] = l_i[r];
      }
    }
  }
}

// ============================ merge kernel ============================
// One thread per output element of split q-blocks (qb 4..15): combine <=4 partials.
__global__ __launch_bounds__(256) void merge_kernel(const unsigned short* __restrict__ Opart,
                                                    const float* __restrict__ mlpart,
                                                    float* __restrict__ out) {
  const int rp  = blockIdx.x * 2 + (threadIdx.x >> 7);  // row-pair id, 0..24575
  const int b   = rp / 1536;
  const int r2  = rp - b * 1536;
  const int qp  = r2 >> 7;                // 0..11 -> qb = 4+qp
  const int row = r2 & 127;
  const int d   = threadIdx.x & 127;
  const int qb  = qp + 4;
  const int g   = (qp < 4) ? 2 : (qp < 8) ? 3 : 4;
  const int s0  = b * SLOTS_PER_B + slot_base(qb);

  float m[4], l[4];
  float M = -1e30f;
  for (int k = 0; k < g; ++k) {
    const float* ml = mlpart + (size_t)(s0 + k) * ML_FLOATS;
    m[k] = ml[row];
    l[k] = ml[128 + row];
    M = fmaxf(M, m[k]);
  }
  float num = 0.f, den = 0.f;
  for (int k = 0; k < g; ++k) {
    float a = EXP2F(m[k] - M);
    num += a * bf2f(Opart[(size_t)(s0 + k) * OPART_SHORTS + (size_t)row * 128 + d]);
    den += a * l[k];
  }
  out[((size_t)b * SEQ_T + qb * 128 + row) * HDIM + d] = num / den;
}

// ============================ R5 fallback (16MB ws) ============================
__global__ __launch_bounds__(512, 4) void attn_fast(const float* __restrict__ x,
                                                    const unsigned short* __restrict__ kbuf,
                                                    const unsigned short* __restrict__ vbuf,
                                                    float* __restrict__ out) {
  const int b    = blockIdx.y;
  const int qblk = (int)gridDim.x - 1 - (int)blockIdx.x;
  const int qb0  = qblk << 6;
  const int tid  = threadIdx.x;
  const int wave = tid >> 6;
  const int lane = tid & 63;
  const int low  = lane & 15;
  const int quad = lane >> 4;
  const int qt   = wave & 3;
  const int half = wave >> 2;
  const int q0   = qb0 + (qt << 4);

  __shared__ __align__(16) unsigned char smem[43008];
  unsigned short* Ks = (unsigned short*)smem;
  unsigned short* Vt = (unsigned short*)(smem + 16384);
  unsigned short* Ps = (unsigned short*)(smem + 32768);
  float* Om = (float*)smem;
  float* Ml = (float*)(smem + 33792);

  const float* xb = x + (size_t)b * (SEQ_T * 3 * HDIM);
  const unsigned short* kt = kbuf + (size_t)b * NTILES * TILE_SHORTS;
  const unsigned short* vt = vbuf + (size_t)b * NTILES * TILE_SHORTS;

  const float qs = 0.08838834764831845f * 1.4426950408889634f;
  short8 qa[4];
  {
    const float* qrow = xb + (size_t)(q0 + low) * 384 + 128;
    for (int kc = 0; kc < 4; ++kc) {
      float4v f0 = *(const float4v*)(qrow + kc * 32 + quad * 8);
      float4v f1 = *(const float4v*)(qrow + kc * 32 + quad * 8 + 4);
      uint4v u = { bfpack2(f0[0] * qs, f0[1] * qs), bfpack2(f0[2] * qs, f0[3] * qs),
                   bfpack2(f1[0] * qs, f1[1] * qs), bfpack2(f1[2] * qs, f1[3] * qs) };
      qa[kc] = __builtin_bit_cast(short8, u);
    }
  }
  float4v accv[8];
  for (int i = 0; i < 8; ++i) accv[i] = (float4v){0.f, 0.f, 0.f, 0.f};
  float m_i[4] = {-1e30f, -1e30f, -1e30f, -1e30f};
  float l_i[4] = {0.f, 0.f, 0.f, 0.f};

  const int nsuper = qblk + 1;
  for (int s = 0; s < nsuper; ++s) {
    __syncthreads();
    {
      const unsigned short* ksrc = kt + (size_t)s * TILE_SHORTS;
      const unsigned short* vsrc = vt + (size_t)s * TILE_SHORTS;
      int ch = wave * 2;
      stage16(ksrc + (size_t)ch * 512 + lane * 8,       Ks + ch * 512);
      stage16(ksrc + (size_t)(ch + 1) * 512 + lane * 8, Ks + (ch + 1) * 512);
      stage16(vsrc + (size_t)ch * 512 + lane * 8,       Vt + ch * 512);
      stage16(vsrc + (size_t)(ch + 1) * 512 + lane * 8, Vt + (ch + 1) * 512);
    }
    __syncthreads();

    const int c0 = (s << 6) + (half << 5);
    if (c0 <= q0 + 15) {
      const int Ra = (half << 5) + low;
      const int Rb = Ra + 16;
      float4v s0 = {0.f,0.f,0.f,0.f}, s1 = {0.f,0.f,0.f,0.f};
      for (int kc = 0; kc < 4; ++kc) {
        short8 kf0 = *(const short8*)&Ks[Ra * 128 + (((kc * 4 + quad) + Ra) & 15) * 8];
        short8 kf1 = *(const short8*)&Ks[Rb * 128 + (((kc * 4 + quad) + Rb) & 15) * 8];
        s0 = __builtin_amdgcn_mfma_f32_16x16x32_bf16(qa[kc], kf0, s0, 0, 0, 0);
        s1 = __builtin_amdgcn_mfma_f32_16x16x32_bf16(qa[kc], kf1, s1, 0, 0, 0);
      }
      if (c0 + 31 > q0) {
        for (int r = 0; r < 4; ++r) {
          int qrow = q0 + quad * 4 + r;
          s0[r] = (c0 + low      <= qrow) ? s0[r] : -1e30f;
          s1[r] = (c0 + 16 + low <= qrow) ? s1[r] : -1e30f;
        }
      }
      float rmax[4], alpha[4];
      for (int r = 0; r < 4; ++r) rmax[r] = dpp_max16(fmaxf(s0[r], s1[r]));
      for (int r = 0; r < 4; ++r) {
        float mn = fmaxf(m_i[r], rmax[r]);
        alpha[r] = EXP2F(m_i[r] - mn);
        m_i[r]   = mn;
      }
      for (int r = 0; r < 4; ++r) {
        s0[r] = EXP2F(s0[r] - m_i[r]);
        s1[r] = EXP2F(s1[r] - m_i[r]);
      }
      float rs[4];
      for (int r = 0; r < 4; ++r) rs[r] = dpp_sum16(s0[r] + s1[r]);
      for (int r = 0; r < 4; ++r) l_i[r] = l_i[r] * alpha[r] + rs[r];
      for (int nt = 0; nt < 8; ++nt)
        for (int r = 0; r < 4; ++r) accv[nt][r] *= alpha[r];

      unsigned short* pw = Ps + wave * 640;
      for (int r = 0; r < 4; ++r) {
        int row = quad * 4 + r;
        pw[row * 40 + low]      = f2bf(s0[r]);
        pw[row * 40 + 16 + low] = f2bf(s1[r]);
      }
      short8 pa = *(const short8*)&pw[low * 40 + quad * 8];

      const int ub = (half << 2) + quad;
      for (int nt = 0; nt < 8; ++nt) {
        int d = nt * 16 + low;
        short8 vf = *(const short8*)&Vt[d * 64 + ((ub + d) & 7) * 8];
        accv[nt] = __builtin_amdgcn_mfma_f32_16x16x32_bf16(pa, vf, accv[nt], 0, 0, 0);
      }
    }
  }

  __syncthreads();
  if (half == 1) {
    float* om = Om + qt * 2112;
    for (int nt = 0; nt < 8; ++nt)
      for (int r = 0; r < 4; ++r)
        om[(quad * 4 + r) * 132 + nt * 16 + low] = accv[nt][r];
    if (low == 0) {
      for (int r = 0; r < 4; ++r) {
        Ml[qt * 32 + quad * 4 + r]      = m_i[r];
        Ml[qt * 32 + 16 + quad * 4 + r] = l_i[r];
      }
    }
  }
  __syncthreads();
  if (half == 0) {
    float aA[4], aB[4], linv[4];
    for (int r = 0; r < 4; ++r) {
      float mB = Ml[qt * 32 + quad * 4 + r];
      float lB = Ml[qt * 32 + 16 + quad * 4 + r];
      float mN = fmaxf(m_i[r], mB);
      aA[r] = EXP2F(m_i[r] - mN);
      aB[r] = EXP2F(mB - mN);
      linv[r] = 1.f / (l_i[r] * aA[r] + lB * aB[r]);
    }
    const float* om = Om + qt * 2112;
    float* ob = out + ((size_t)b * SEQ_T + q0) * HDIM;
    for (int nt = 0; nt < 8; ++nt)
      for (int r = 0; r < 4; ++r) {
        float o = accv[nt][r] * aA[r] + om[(quad * 4 + r) * 132 + nt * 16 + low] * aB[r];
        ob[(size_t)(quad * 4 + r) * HDIM + nt * 16 + low] = o * linv[r];
      }
  }
}

// ============================ no-ws fallback (R4) ============================
__global__ __launch_bounds__(512, 4) void attn_fb(const float* __restrict__ x,
                                                  float* __restrict__ out) {
  const int b    = blockIdx.y;
  const int qblk = (int)gridDim.x - 1 - (int)blockIdx.x;
  const int qb0  = qblk << 6;
  const int tid  = threadIdx.x;
  const int wave = tid >> 6;
  const int lane = tid & 63;
  const int low  = lane & 15;
  const int quad = lane >> 4;
  const int qt   = wave & 3;
  const int half = wave >> 2;
  const int q0   = qb0 + (qt << 4);
  __shared__ __align__(16) unsigned char smem[48128];
  unsigned short* Ks = (unsigned short*)smem;
  unsigned short* Vt = (unsigned short*)(smem + 17408);
  unsigned short* Ps = (unsigned short*)(smem + 37888);
  float* Om = (float*)smem;
  float* Ml = (float*)(smem + 33792);
  const float* xb = x + (size_t)b * (SEQ_T * 3 * HDIM);
  const float qs = 0.08838834764831845f * 1.4426950408889634f;
  short8 qa[4];
  {
    const float* qrow = xb + (size_t)(q0 + low) * 384 + 128;
    for (int kc = 0; kc < 4; ++kc) {
      float4v f0 = *(const float4v*)(qrow + kc * 32 + quad * 8);
      float4v f1 = *(const float4v*)(qrow + kc * 32 + quad * 8 + 4);
      uint4v u = { bfpack2(f0[0] * qs, f0[1] * qs), bfpack2(f0[2] * qs, f0[3] * qs),
                   bfpack2(f1[0] * qs, f1[1] * qs), bfpack2(f1[2] * qs, f1[3] * qs) };
      qa[kc] = __builtin_bit_cast(short8, u);
    }
  }
  float4v accv[8];
  for (int i = 0; i < 8; ++i) accv[i] = (float4v){0.f, 0.f, 0.f, 0.f};
  float m_i[4] = {-1e30f, -1e30f, -1e30f, -1e30f};
  float l_i[4] = {0.f, 0.f, 0.f, 0.f};
  const int nsuper = qblk + 1;
  for (int s = 0; s < nsuper; ++s) {
    const int r0 = s << 6;
    __syncthreads();
    for (int i = 0; i < 4; ++i) {
      int f = tid + (i << 9);
      int row = f >> 5;
      int c4 = (f & 31) << 2;
      float4v kf = *(const float4v*)(xb + (size_t)(r0 + row) * 384 + c4);
      *(uint2*)&Ks[(row >> 5) * 4352 + (row & 31) * 136 + c4] =
          make_uint2(bfpack2(kf[0], kf[1]), bfpack2(kf[2], kf[3]));
    }
    {
      int kb = tid >> 5, db = tid & 31;
      int til = kb >> 3, kbl = kb & 7;
      const float* vbase = xb + (size_t)(r0 + 4 * kb) * 384 + 256 + 4 * db;
      float4v v0 = *(const float4v*)(vbase);
      float4v v1 = *(const float4v*)(vbase + 384);
      float4v v2 = *(const float4v*)(vbase + 768);
      float4v v3 = *(const float4v*)(vbase + 1152);
      unsigned short* vv = Vt + til * 5120;
      for (int j = 0; j < 4; ++j) {
        int d = 4 * db + j;
        int pb = ((kbl >> 1) + (d >> 3)) & 3;
        *(uint2*)&vv[d * 40 + pb * 8 + (kbl & 1) * 4] =
            make_uint2(bfpack2(v0[j], v1[j]), bfpack2(v2[j], v3[j]));
      }
    }
    __syncthreads();
    const int c0 = r0 + (half << 5);
    if (c0 <= q0 + 15) {
      const unsigned short* Ksp = Ks + half * 4352;
      const unsigned short* Vtp = Vt + half * 5120;
      float4v s0 = {0.f,0.f,0.f,0.f}, s1 = {0.f,0.f,0.f,0.f};
      for (int kc = 0; kc < 4; ++kc) {
        short8 kf0 = *(const short8*)&Ksp[low * 136 + kc * 32 + quad * 8];
        short8 kf1 = *(const short8*)&Ksp[(16 + low) * 136 + kc * 32 + quad * 8];
        s0 = __builtin_amdgcn_mfma_f32_16x16x32_bf16(qa[kc], kf0, s0, 0, 0, 0);
        s1 = __builtin_amdgcn_mfma_f32_16x16x32_bf16(qa[kc], kf1, s1, 0, 0, 0);
      }
      if (c0 + 31 > q0) {
        for (int r = 0; r < 4; ++r) {
          int qrow = q0 + quad * 4 + r;
          s0[r] = (c0 + low      <= qrow) ? s0[r] : -1e30f;
          s1[r] = (c0 + 16 + low <= qrow) ? s1[r] : -1e30f;
        }
      }
      float rmax[4], alpha[4];
      for (int r = 0; r < 4; ++r) rmax[r] = dpp_max16(fmaxf(s0[r], s1[r]));
      for (int r = 0; r < 4; ++r) {
        float mn = fmaxf(m_i[r], rmax[r]);
        alpha[r] = EXP2F(m_i[r] - mn);
        m_i[r] = mn;
      }
      for (int r = 0; r < 4; ++r) {
        s0[r] = EXP2F(s0[r] - m_i[r]);
        s1[r] = EXP2F(s1[r] - m_i[r]);
      }
      float rs[4];
      for (int r = 0; r < 4; ++r) rs[r] = dpp_sum16(s0[r] + s1[r]);
      for (int r = 0; r < 4; ++r) l_i[r] = l_i[r] * alpha[r] + rs[r];
      for (int nt = 0; nt < 8; ++nt)
        for (int r = 0; r < 4; ++r) accv[nt][r] *= alpha[r];
      unsigned short* pw = Ps + wave * 640;
      for (int r = 0; r < 4; ++r) {
        int row = quad * 4 + r;
        pw[row * 40 + low]      = f2bf(s0[r]);
        pw[row * 40 + 16 + low] = f2bf(s1[r]);
      }
      short8 pa = *(const short8*)&pw[low * 40 + quad * 8];
      for (int nt = 0; nt < 8; ++nt) {
        int d = nt * 16 + low;
        int pb = (quad + (d >> 3)) & 3;
        short8 vf = *(const short8*)&Vtp[d * 40 + pb * 8];
        accv[nt] = __builtin_amdgcn_mfma_f32_16x16x32_bf16(pa, vf, accv[nt], 0, 0, 0);
      }
    }
  }
  __syncthreads();
  if (half == 1) {
    float* om = Om + qt * 2112;
    for (int nt = 0; nt < 8; ++nt)
      for (int r = 0; r < 4; ++r)
        om[(quad * 4 + r) * 132 + nt * 16 + low] = accv[nt][r];
    if (low == 0) {
      for (int r = 0; r < 4; ++r) {
        Ml[qt * 32 + quad * 4 + r]      = m_i[r];
        Ml[qt * 32 + 16 + quad * 4 + r] = l_i[r];
      }
    }
  }
  __syncthreads();
  if (half == 0) {
    float aA[4], aB[4], linv[4];
    for (int r = 0; r < 4; ++r) {
      float mB = Ml[qt * 32 + quad * 4 + r];
      float lB = Ml[qt * 32 + 16 + quad * 4 + r];
      float mN = fmaxf(m_i[r], mB);
      aA[r] = EXP2F(m_i[r] - mN);
      aB[r] = EXP2F(mB - mN);
      linv[r] = 1.f / (l_i[r] * aA[r] + lB * aB[r]);
    }
    const float* om = Om + qt * 2112;
    float* ob = out + ((size_t)b * SEQ_T + q0) * HDIM;
    for (int nt = 0; nt < 8; ++nt)
      for (int r = 0; r < 4; ++r) {
        float o = accv[nt][r] * aA[r] + om[(quad * 4 + r) * 132 + nt * 16 + low] * aB[r];
        ob[(size_t)(quad * 4 + r) * HDIM + nt * 16 + low] = o * linv[r];
      }
  }
}

extern "C" void kernel_launch(void* const* d_in, const int* in_sizes, int n_in,
                              void* d_out, int out_size, void* d_ws, size_t ws_size,
                              hipStream_t stream) {
  const float* x = (const float*)d_in[0];
  float* out = (float*)d_out;
  const size_t PRE_BYTES   = (size_t)NB * NTILES * TILE_SHORTS * 2 * sizeof(unsigned short); // 16 MB
  const size_t NSLOTS      = (size_t)NB * SLOTS_PER_B;                                        // 576
  const size_t OPART_BYTES = NSLOTS * OPART_SHORTS * sizeof(unsigned short);                  // ~18.9 MB
  const size_t ML_BYTES    = NSLOTS * ML_FLOATS * sizeof(float);                              // ~0.6 MB

  if (ws_size >= PRE_BYTES + OPART_BYTES + ML_BYTES) {
    unsigned short* kbuf  = (unsigned short*)d_ws;
    unsigned short* vbuf  = kbuf + (size_t)NB * NTILES * TILE_SHORTS;
    unsigned short* Opart = (unsigned short*)((char*)d_ws + PRE_BYTES);
    float*          mlp   = (float*)((char*)d_ws + PRE_BYTES + OPART_BYTES);
    hipLaunchKernelGGL(prepass_kernel, dim3(NB * NTILES * 1024 / 256), dim3(256), 0, stream,
                       x, kbuf, vbuf);
    hipLaunchKernelGGL(attn_chunk, dim3(NB * CHUNKS_PER_B), dim3(512), 0, stream,
                       x, kbuf, vbuf, Opart, mlp, out);
    hipLaunchKernelGGL(merge_kernel, dim3(NB * 12 * 128 / 2), dim3(256), 0, stream,
                       Opart, mlp, out);
  } else if (ws_size >= PRE_BYTES) {
    unsigned short* kbuf = (unsigned short*)d_ws;
    unsigned short* vbuf = kbuf + (size_t)NB * NTILES * TILE_SHORTS;
    hipLaunchKernelGGL(prepass_kernel, dim3(NB * NTILES * 1024 / 256), dim3(256), 0, stream,
                       x, kbuf, vbuf);
    hipLaunchKernelGGL(attn_fast, dim3(SEQ_T / 64, NB), dim3(512), 0, stream,
                       x, kbuf, vbuf, out);
  } else {
    hipLaunchKernelGGL(attn_fb, dim3(SEQ_T / 64, NB), dim3(512), 0, stream, x, out);
  }
}